// Round 2
// baseline (646.809 us; speedup 1.0000x reference)
//
#include <hip/hip_runtime.h>

// MADE / PixelCNN autoregressive inverse (all tensors fp32, per reference):
// The reference's 64-iteration fixed-point scan converges pixel p at
// iteration p+1 (masked convs are strictly causal in raster order), so the
// whole scan equals ONE sequential raster decode computing each conv layer
// only at the new pixel, with cached h0/h1 activations from earlier pixels.
//
// Grid: 32 blocks (one per batch item). Block: 640 threads = (tap 0..4) x
// (net mu/lv) x (ch 0..63). Each thread holds one tap column of W1 and W2
// (64+64 fp32 registers). Activations are fp32 in LDS with rolling 2-row,
// zero-padded buffers (branch-free SAME padding). Within-wave LDS activation
// reads are same-address broadcasts (conflict-free); small-weight LDS reads
// are lane-contiguous (conflict-free).

#define NT 640

__device__ __forceinline__ float elu(float x) { return x > 0.f ? x : expm1f(x); }

__global__ __launch_bounds__(NT, 1) void made_ar_decode_k(
    const float* __restrict__ x,
    const float* __restrict__ mw0, const float* __restrict__ mb0,
    const float* __restrict__ mw1, const float* __restrict__ mb1,
    const float* __restrict__ mw2, const float* __restrict__ mb2,
    const float* __restrict__ mwo, const float* __restrict__ mbo,
    const float* __restrict__ lw0, const float* __restrict__ lb0,
    const float* __restrict__ lw1, const float* __restrict__ lb1,
    const float* __restrict__ lw2, const float* __restrict__ lb2,
    const float* __restrict__ lwo, const float* __restrict__ lbo,
    float* __restrict__ out)
{
  const int b   = blockIdx.x;
  const int tid = threadIdx.x;
  const int tap = tid >> 7;          // 0..4; tap 4 threads = pixel-local workers
  const int net = (tid >> 6) & 1;    // 0 = mu, 1 = lv
  const int ch  = tid & 63;

  // mask-B tap t -> kernel pos (kh,kw), offset (dr,dc)=(kh-1,kw-1):
  // taps (0,0)(0,1)(0,2)(1,0)(1,1) -> (-1,-1)(-1,0)(-1,1)(0,-1)(0,0)
  const int kh = (tap < 3) ? 0 : 1;
  const int kw = (tap < 3) ? tap : (tap - 3);
  const int dr = (tap < 3) ? -1 : 0;
  const int dc = (tap < 3) ? (tap - 1) : ((tap == 3) ? -1 : 0);

  __shared__ __align__(16) float yb[9][10][4];       // rows -1..7 -> 0..8, cols -1..8 -> 0..9 (pads stay 0)
  __shared__ __align__(16) float h0b[2][2][10][64];  // [net][row&1][col+1][ch]
  __shared__ __align__(16) float h1b[2][2][10][64];
  __shared__ float red[512];
  __shared__ float red2[512];
  __shared__ float outv[2][4];
  __shared__ float xls[256];
  __shared__ float w0a[2][16][64];   // [net][t*4+ic][ch]  (lane-contiguous)
  __shared__ float bza[2][3][64];    // [net][layer][ch]
  __shared__ float woa[2][4][64];    // [net][oc][ch]
  __shared__ float boa[2][4];

  for (int k = tid; k < 9*10*4; k += NT) (&yb[0][0][0])[k] = 0.f;
  for (int k = tid; k < 2*2*10*64; k += NT) {
    (&h0b[0][0][0][0])[k] = 0.f;
    (&h1b[0][0][0][0])[k] = 0.f;
  }
  if (tid < 256) xls[tid] = x[b*256 + tid];          // [c][i][j] flat = c*64 + p

  // ---- stage small weights in LDS ----
  {
    const int KHt[4] = {0,0,0,1};
    const int KWt[4] = {0,1,2,0};
    for (int k = tid; k < 2*16*64; k += NT) {        // mask-A taps of w0
      int n = k >> 10, rem = k & 1023;
      int t4ic = rem >> 6, c = rem & 63;
      int t = t4ic >> 2, ic = t4ic & 3;
      const float* w0g = n ? lw0 : mw0;
      w0a[n][t4ic][c] = w0g[((c*4 + ic)*3 + KHt[t])*3 + KWt[t]];
    }
    for (int k = tid; k < 2*3*64; k += NT) {
      int n = k / 192, rem = k % 192, l = rem >> 6, c = rem & 63;
      const float* bp = n ? (l==0 ? lb0 : (l==1 ? lb1 : lb2))
                          : (l==0 ? mb0 : (l==1 ? mb1 : mb2));
      bza[n][l][c] = bp[c];
    }
    for (int k = tid; k < 2*4*64; k += NT) {
      int n = k >> 8, rem = k & 255, oc = rem >> 6, c = rem & 63;
      woa[n][oc][c] = (n ? lwo : mwo)[oc*64 + c];
    }
    if (tid < 8) boa[tid>>2][tid&3] = ((tid>>2) ? lbo : mbo)[tid&3];
  }

  // ---- per-thread register weights: one tap column of W1 and W2 ----
  const float* w1g = net ? lw1 : mw1;
  const float* w2g = net ? lw2 : mw2;
  float w1r[64], w2r[64];
#pragma unroll
  for (int q = 0; q < 64; ++q) {
    w1r[q] = w1g[((ch*64 + q)*3 + kh)*3 + kw];   // W1[o=ch][i=q][kh][kw], OIHW
    w2r[q] = w2g[((ch*64 + q)*3 + kh)*3 + kw];
  }

  __syncthreads();

  float lsacc = 0.f;

#pragma unroll 1
  for (int p = 0; p < 64; ++p) {
    const int i  = p >> 3, j = p & 7;
    const int sl = i & 1;

    // ---- P1: taps0-3 h1-partials (read h0 at raster < p); h0(p) on tap4
    if (tid < 512) {
      const float4* src = reinterpret_cast<const float4*>(&h0b[net][(i + dr) & 1][j + dc + 1][0]);
      float a0 = 0.f, a1 = 0.f, a2 = 0.f, a3 = 0.f;
#pragma unroll
      for (int q = 0; q < 16; ++q) {
        float4 v = src[q];
        a0 += w1r[4*q+0] * v.x; a1 += w1r[4*q+1] * v.y;
        a2 += w1r[4*q+2] * v.z; a3 += w1r[4*q+3] * v.w;
      }
      red[tid] = (a0 + a1) + (a2 + a3);
    } else {
      float acc = bza[net][0][ch];
      const int KHt[4] = {0,0,0,1};
      const int KWt[4] = {0,1,2,0};
#pragma unroll
      for (int t = 0; t < 4; ++t) {
        const float* yv = yb[i + KHt[t]][j + KWt[t]];  // padded coords (i+kh-1)+1, (j+kw-1)+1
        acc += w0a[net][t*4+0][ch]*yv[0] + w0a[net][t*4+1][ch]*yv[1]
             + w0a[net][t*4+2][ch]*yv[2] + w0a[net][t*4+3][ch]*yv[3];
      }
      h0b[net][sl][j + 1][ch] = elu(acc);
    }
    __syncthreads();

    // ---- P2: taps0-3 h2-partials (read h1 < p); h1(p) reduce + center dot on tap4
    if (tid < 512) {
      const float4* src = reinterpret_cast<const float4*>(&h1b[net][(i + dr) & 1][j + dc + 1][0]);
      float a0 = 0.f, a1 = 0.f, a2 = 0.f, a3 = 0.f;
#pragma unroll
      for (int q = 0; q < 16; ++q) {
        float4 v = src[q];
        a0 += w2r[4*q+0] * v.x; a1 += w2r[4*q+1] * v.y;
        a2 += w2r[4*q+2] * v.z; a3 += w2r[4*q+3] * v.w;
      }
      red2[tid] = (a0 + a1) + (a2 + a3);
    } else {
      const float4* src = reinterpret_cast<const float4*>(&h0b[net][sl][j + 1][0]);
      float a0 = 0.f, a1 = 0.f, a2 = 0.f, a3 = 0.f;
#pragma unroll
      for (int q = 0; q < 16; ++q) {
        float4 v = src[q];
        a0 += w1r[4*q+0] * v.x; a1 += w1r[4*q+1] * v.y;   // center tap of W1
        a2 += w1r[4*q+2] * v.z; a3 += w1r[4*q+3] * v.w;
      }
      const int r = tid - 512;
      float acc = bza[net][1][ch] + red[r] + red[r+128] + red[r+256] + red[r+384]
                + ((a0 + a1) + (a2 + a3));
      h1b[net][sl][j + 1][ch] = elu(acc);
    }
    __syncthreads();

    // ---- P3: h2(p) reduce + center dot, then 1x1 out-conv via wave shuffles
    if (tid >= 512) {
      const float4* src = reinterpret_cast<const float4*>(&h1b[net][sl][j + 1][0]);
      float a0 = 0.f, a1 = 0.f, a2 = 0.f, a3 = 0.f;
#pragma unroll
      for (int q = 0; q < 16; ++q) {
        float4 v = src[q];
        a0 += w2r[4*q+0] * v.x; a1 += w2r[4*q+1] * v.y;   // center tap of W2
        a2 += w2r[4*q+2] * v.z; a3 += w2r[4*q+3] * v.w;
      }
      const int r = tid - 512;
      float acc = bza[net][2][ch] + red2[r] + red2[r+128] + red2[r+256] + red2[r+384]
                + ((a0 + a1) + (a2 + a3));
      float h2 = elu(acc);
      float p0 = woa[net][0][ch]*h2, p1 = woa[net][1][ch]*h2;
      float p2 = woa[net][2][ch]*h2, p3 = woa[net][3][ch]*h2;
#pragma unroll
      for (int off = 32; off; off >>= 1) {
        p0 += __shfl_xor(p0, off, 64);
        p1 += __shfl_xor(p1, off, 64);
        p2 += __shfl_xor(p2, off, 64);
        p3 += __shfl_xor(p3, off, 64);
      }
      if (ch == 0) { outv[net][0] = p0; outv[net][1] = p1; outv[net][2] = p2; outv[net][3] = p3; }
    }
    __syncthreads();

    // ---- epilogue: y(p) = (x - mu) / (exp(logstd) + eps)
    if (tid == 0) {
#pragma unroll
      for (int c = 0; c < 4; ++c) {
        float mu = outv[0][c] + boa[0][c];
        float ls = 0.5f * (outv[1][c] + boa[1][c]);
        float yv = (xls[c*64 + p] - mu) / (expf(ls) + 1e-12f);
        yb[i + 1][j + 1][c] = yv;
        out[(b*4 + c)*64 + p] = yv;
        lsacc += ls;
      }
    }
    __syncthreads();
  }

  if (tid == 0) out[32*4*64 + b] = lsacc;
}

extern "C" void kernel_launch(void* const* d_in, const int* in_sizes, int n_in,
                              void* d_out, int out_size, void* d_ws, size_t ws_size,
                              hipStream_t stream) {
  (void)in_sizes; (void)n_in; (void)out_size; (void)d_ws; (void)ws_size;
  made_ar_decode_k<<<dim3(32), dim3(NT), 0, stream>>>(
      (const float*)d_in[0],
      (const float*)d_in[1],  (const float*)d_in[2],
      (const float*)d_in[3],  (const float*)d_in[4],
      (const float*)d_in[5],  (const float*)d_in[6],
      (const float*)d_in[7],  (const float*)d_in[8],
      (const float*)d_in[9],  (const float*)d_in[10],
      (const float*)d_in[11], (const float*)d_in[12],
      (const float*)d_in[13], (const float*)d_in[14],
      (const float*)d_in[15], (const float*)d_in[16],
      (float*)d_out);
}

// Round 3
// 269.106 us; speedup vs baseline: 2.4035x; 2.4035x over previous
//
#include <hip/hip_runtime.h>

// MADE / PixelCNN autoregressive inverse (all fp32, per reference):
// one sequential raster decode; each layer computed only at the new pixel
// with cached h0/h1 rows. Verified bit-exact (absmax 0.0) in round 2.
//
// Round-3 restructure: round 2 spilled 128 weight floats/thread to scratch
// (VGPR_Count 84, WRITE_SIZE 11.9 MB = spill stores). Now 1024 threads =
// (role: W1|W2) x (tap 0..3) x (net mu|lv) x (ch 0..63); each thread holds
// one 64-float off-center tap column + one 16-float center-column quarter
// (80 floats + ~30 overhead <= 128 VGPR cap at 16 waves/CU). W2 off-center
// partials (vs h1 at raster < p) run concurrently with W1's, so no thread
// ever needs both matrices.

#define NT 1024

__device__ __forceinline__ float elu(float x) { return x > 0.f ? x : expm1f(x); }

__global__ __launch_bounds__(NT) void made_ar_decode_k(
    const float* __restrict__ x,
    const float* __restrict__ mw0, const float* __restrict__ mb0,
    const float* __restrict__ mw1, const float* __restrict__ mb1,
    const float* __restrict__ mw2, const float* __restrict__ mb2,
    const float* __restrict__ mwo, const float* __restrict__ mbo,
    const float* __restrict__ lw0, const float* __restrict__ lb0,
    const float* __restrict__ lw1, const float* __restrict__ lb1,
    const float* __restrict__ lw2, const float* __restrict__ lb2,
    const float* __restrict__ lwo, const float* __restrict__ lbo,
    float* __restrict__ out)
{
  const int b    = blockIdx.x;
  const int tid  = threadIdx.x;
  const int role = tid >> 9;          // 0: W1 / h1-partials, 1: W2 / h2-partials
  const int tap  = (tid >> 7) & 3;    // off-center taps NW,N,NE,W
  const int net  = (tid >> 6) & 1;    // 0 = mu, 1 = lv
  const int ch   = tid & 63;

  // tap -> kernel pos (kh,kw) and spatial offset (dr,dc) = (kh-1, kw-1)
  const int kh = (tap < 3) ? 0 : 1;
  const int kw = (tap < 3) ? tap : 0;
  const int dr = (tap < 3) ? -1 : 0;
  const int dc = (tap < 3) ? (tap - 1) : -1;

  __shared__ __align__(16) float yb[9][10][4];       // rows -1..7 -> 0..8, cols -1..8 -> 0..9 (pads stay 0)
  __shared__ __align__(16) float h0b[2][2][10][64];  // [net][row&1][col+1][ch]
  __shared__ __align__(16) float h1b[2][2][10][64];
  __shared__ float red1[4][2][64], red2[4][2][64];   // off-center partials [tap][net][ch]
  __shared__ float redc1[4][2][64], redc2[4][2][64]; // center quarter partials
  __shared__ float outv[2][4];
  __shared__ float xls[256];
  __shared__ float w0a[2][16][64];   // [net][t*4+ic][ch]  (lane-contiguous)
  __shared__ float bza[2][3][64];    // [net][layer][ch]
  __shared__ float woa[2][4][64];    // [net][oc][ch]
  __shared__ float boa[2][4];

  for (int k = tid; k < 9*10*4; k += NT) (&yb[0][0][0])[k] = 0.f;
  for (int k = tid; k < 2*2*10*64; k += NT) {
    (&h0b[0][0][0][0])[k] = 0.f;
    (&h1b[0][0][0][0])[k] = 0.f;
  }
  if (tid < 256) xls[tid] = x[b*256 + tid];          // [c][i][j] flat = c*64 + p

  // ---- stage small weights in LDS ----
  {
    const int KHt[4] = {0,0,0,1};
    const int KWt[4] = {0,1,2,0};
    for (int k = tid; k < 2*16*64; k += NT) {        // mask-A taps of w0
      int n = k >> 10, rem = k & 1023;
      int t4ic = rem >> 6, c = rem & 63;
      int t = t4ic >> 2, ic = t4ic & 3;
      const float* w0g = n ? lw0 : mw0;
      w0a[n][t4ic][c] = w0g[((c*4 + ic)*3 + KHt[t])*3 + KWt[t]];
    }
    for (int k = tid; k < 2*3*64; k += NT) {
      int n = k / 192, rem = k % 192, l = rem >> 6, c = rem & 63;
      const float* bp = n ? (l==0 ? lb0 : (l==1 ? lb1 : lb2))
                          : (l==0 ? mb0 : (l==1 ? mb1 : mb2));
      bza[n][l][c] = bp[c];
    }
    for (int k = tid; k < 2*4*64; k += NT) {
      int n = k >> 8, rem = k & 255, oc = rem >> 6, c = rem & 63;
      woa[n][oc][c] = (n ? lwo : mwo)[oc*64 + c];
    }
    if (tid < 8) boa[tid>>2][tid&3] = ((tid>>2) ? lbo : mbo)[tid&3];
  }

  // ---- per-thread register weights (80 floats total) ----
  const float* wg = role ? (net ? lw2 : mw2) : (net ? lw1 : mw1);
  float wcol[64];   // W[ch, :, kh, kw]  (off-center tap column, OIHW)
  float wq[16];     // W[ch, 16*tap .. 16*tap+15, 1, 1]  (center-column quarter)
#pragma unroll
  for (int q = 0; q < 64; ++q) wcol[q] = wg[((ch*64 + q)*3 + kh)*3 + kw];
#pragma unroll
  for (int k = 0; k < 16; ++k)  wq[k] = wg[((ch*64 + 16*tap + k)*3 + 1)*3 + 1];

  __syncthreads();

  float lsacc = 0.f;

#pragma unroll 1
  for (int p = 0; p < 64; ++p) {
    const int i  = p >> 3, j = p & 7;
    const int sl = i & 1;

    // ---- P1: all off-center partials; h0(p) on tid<128
    if (tid < 128) {   // role 0, tap 0
      const int KHt[4] = {0,0,0,1};
      const int KWt[4] = {0,1,2,0};
      float acc = bza[net][0][ch];
#pragma unroll
      for (int t = 0; t < 4; ++t) {
        const float* yv = yb[i + KHt[t]][j + KWt[t]];
        acc += w0a[net][t*4+0][ch]*yv[0] + w0a[net][t*4+1][ch]*yv[1]
             + w0a[net][t*4+2][ch]*yv[2] + w0a[net][t*4+3][ch]*yv[3];
      }
      h0b[net][sl][j + 1][ch] = elu(acc);
    }
    {
      const float* actb = role ? &h1b[net][(i + dr) & 1][j + dc + 1][0]
                               : &h0b[net][(i + dr) & 1][j + dc + 1][0];
      const float4* src = reinterpret_cast<const float4*>(actb);
      float a0 = 0.f, a1 = 0.f, a2 = 0.f, a3 = 0.f;
#pragma unroll
      for (int q = 0; q < 16; ++q) {
        float4 v = src[q];
        a0 += wcol[4*q+0] * v.x; a1 += wcol[4*q+1] * v.y;
        a2 += wcol[4*q+2] * v.z; a3 += wcol[4*q+3] * v.w;
      }
      (role ? red2 : red1)[tap][net][ch] = (a0 + a1) + (a2 + a3);
    }
    __syncthreads();

    // ---- P2: W1-center quarter dots (role 0)
    if (role == 0) {
      const float4* h0p = reinterpret_cast<const float4*>(&h0b[net][sl][j + 1][0]);
      float a0 = 0.f, a1 = 0.f, a2 = 0.f, a3 = 0.f;
#pragma unroll
      for (int kk = 0; kk < 4; ++kk) {
        float4 v = h0p[tap*4 + kk];
        a0 += wq[4*kk+0] * v.x; a1 += wq[4*kk+1] * v.y;
        a2 += wq[4*kk+2] * v.z; a3 += wq[4*kk+3] * v.w;
      }
      redc1[tap][net][ch] = (a0 + a1) + (a2 + a3);
    }
    __syncthreads();

    // ---- P3: h1(p) reduce
    if (tid < 128) {
      float acc = bza[net][1][ch];
#pragma unroll
      for (int t = 0; t < 4; ++t) acc += red1[t][net][ch] + redc1[t][net][ch];
      h1b[net][sl][j + 1][ch] = elu(acc);
    }
    __syncthreads();

    // ---- P4: W2-center quarter dots (role 1)
    if (role == 1) {
      const float4* h1p = reinterpret_cast<const float4*>(&h1b[net][sl][j + 1][0]);
      float a0 = 0.f, a1 = 0.f, a2 = 0.f, a3 = 0.f;
#pragma unroll
      for (int kk = 0; kk < 4; ++kk) {
        float4 v = h1p[tap*4 + kk];
        a0 += wq[4*kk+0] * v.x; a1 += wq[4*kk+1] * v.y;
        a2 += wq[4*kk+2] * v.z; a3 += wq[4*kk+3] * v.w;
      }
      redc2[tap][net][ch] = (a0 + a1) + (a2 + a3);
    }
    __syncthreads();

    // ---- P5: h2(p) reduce + 1x1 out-conv via wave shuffles (2 waves: net0, net1)
    if (tid < 128) {
      float acc = bza[net][2][ch];
#pragma unroll
      for (int t = 0; t < 4; ++t) acc += red2[t][net][ch] + redc2[t][net][ch];
      float h2 = elu(acc);
      float p0 = woa[net][0][ch]*h2, p1 = woa[net][1][ch]*h2;
      float p2 = woa[net][2][ch]*h2, p3 = woa[net][3][ch]*h2;
#pragma unroll
      for (int off = 32; off; off >>= 1) {
        p0 += __shfl_xor(p0, off, 64);
        p1 += __shfl_xor(p1, off, 64);
        p2 += __shfl_xor(p2, off, 64);
        p3 += __shfl_xor(p3, off, 64);
      }
      if (ch == 0) { outv[net][0] = p0; outv[net][1] = p1; outv[net][2] = p2; outv[net][3] = p3; }
    }
    __syncthreads();

    // ---- P6: epilogue  y(p) = (x - mu) / (exp(logstd) + eps)
    if (tid == 0) {
#pragma unroll
      for (int c = 0; c < 4; ++c) {
        float mu = outv[0][c] + boa[0][c];
        float ls = 0.5f * (outv[1][c] + boa[1][c]);
        float yv = (xls[c*64 + p] - mu) / (expf(ls) + 1e-12f);
        yb[i + 1][j + 1][c] = yv;
        out[(b*4 + c)*64 + p] = yv;
        lsacc += ls;
      }
    }
    __syncthreads();
  }

  if (tid == 0) out[32*4*64 + b] = lsacc;
}

extern "C" void kernel_launch(void* const* d_in, const int* in_sizes, int n_in,
                              void* d_out, int out_size, void* d_ws, size_t ws_size,
                              hipStream_t stream) {
  (void)in_sizes; (void)n_in; (void)out_size; (void)d_ws; (void)ws_size;
  made_ar_decode_k<<<dim3(32), dim3(NT), 0, stream>>>(
      (const float*)d_in[0],
      (const float*)d_in[1],  (const float*)d_in[2],
      (const float*)d_in[3],  (const float*)d_in[4],
      (const float*)d_in[5],  (const float*)d_in[6],
      (const float*)d_in[7],  (const float*)d_in[8],
      (const float*)d_in[9],  (const float*)d_in[10],
      (const float*)d_in[11], (const float*)d_in[12],
      (const float*)d_in[13], (const float*)d_in[14],
      (const float*)d_in[15], (const float*)d_in[16],
      (float*)d_out);
}